// Round 1
// baseline (628.443 us; speedup 1.0000x reference)
//
#include <hip/hip_runtime.h>
#include <cmath>

#define NTOK 1024
#define HD   768
#define FF   3072
#define NE   8
#define NSLOT (NTOK * 2)

typedef unsigned short u16;
typedef unsigned int   u32;
typedef __bf16 bf16x8 __attribute__((ext_vector_type(8)));
typedef float  f32x4  __attribute__((ext_vector_type(4)));

__device__ __forceinline__ u16 f2bf(float f) {
  union { float f; u32 u; } v; v.f = f;
  u32 r = v.u + 0x7FFFu + ((v.u >> 16) & 1u);
  return (u16)(r >> 16);
}

// ---------------------------------------------------------------------------
// Router: logits -> top2 -> gates; compact per-expert slot lists; x -> bf16.
// Single block of 1024 threads (one thread per token).
// seg[0..7] = segment start, seg[8..15] = segment count.
// ---------------------------------------------------------------------------
__global__ __launch_bounds__(1024) void router_kernel(
    const float* __restrict__ x, const float* __restrict__ rw,
    u16* __restrict__ xb, int* __restrict__ tos,
    float* __restrict__ gos, int* __restrict__ seg)
{
  __shared__ float rws[HD * NE];   // 24 KB
  __shared__ int counts[NE];
  __shared__ int offs[NE];
  const int t = threadIdx.x;
  for (int i = t; i < HD * NE; i += 1024) rws[i] = rw[i];
  if (t < NE) counts[t] = 0;
  __syncthreads();

  float acc[NE];
#pragma unroll
  for (int e = 0; e < NE; ++e) acc[e] = 0.f;
  const float* xrow = x + (size_t)t * HD;
  u16* xbrow = xb + (size_t)t * HD;
  for (int h = 0; h < HD; ++h) {
    const float xv = xrow[h];
    xbrow[h] = f2bf(xv);
#pragma unroll
    for (int e = 0; e < NE; ++e) acc[e] += xv * rws[h * NE + e];
  }

  // top-2 on logits (softmax is strictly monotone; tie -> lower index, like lax.top_k)
  float v0 = -1e30f, v1 = -1e30f; int i0 = 0, i1 = 0;
#pragma unroll
  for (int e = 0; e < NE; ++e) {
    const float p = acc[e];
    if (p > v0) { v1 = v0; i1 = i0; v0 = p; i0 = e; }
    else if (p > v1) { v1 = p; i1 = e; }
  }
  // renormalized top-2 softmax weights: softmax denom cancels
  const float e1 = expf(v1 - v0);
  const float g0 = 1.0f / (1.0f + e1);
  const float g1 = e1 / (1.0f + e1);

  const int pos0 = atomicAdd(&counts[i0], 1);
  const int pos1 = atomicAdd(&counts[i1], 1);
  __syncthreads();
  if (t == 0) {
    int o = 0;
    for (int e = 0; e < NE; ++e) {
      offs[e] = o; seg[e] = o; seg[NE + e] = counts[e]; o += counts[e];
    }
  }
  __syncthreads();
  const int s0 = offs[i0] + pos0;
  const int s1 = offs[i1] + pos1;
  tos[s0] = t; gos[s0] = g0;
  tos[s1] = t; gos[s1] = g1;
}

// ---------------------------------------------------------------------------
// FFN1: h[slot][f] = gelu( x[token[slot]] @ w1[e] ), bf16 MFMA 16x16x32.
// 64x64 tile per block, BK=32, 4 waves in 2x2 arrangement (32x32 each).
// LDS tiles stored K-contiguous, row stride 40 (pad) for conflict-light b128.
// ---------------------------------------------------------------------------
#define LDA 40

__global__ __launch_bounds__(256) void ffn1_kernel(
    const u16* __restrict__ xb, const float* __restrict__ w1,
    const int* __restrict__ tos, const int* __restrict__ seg,
    u16* __restrict__ hbuf)
{
  const int e   = blockIdx.z;
  const int cnt = seg[NE + e];
  const int m0  = blockIdx.y * 64;
  if (m0 >= cnt) return;
  const int start = seg[e];
  const int n0    = blockIdx.x * 64;

  __shared__ __align__(16) u16 As[64 * LDA];
  __shared__ __align__(16) u16 Bs[64 * LDA];
  __shared__ int toks[64];

  const int tid = threadIdx.x;
  if (tid < 64) toks[tid] = tos[start + min(m0 + tid, cnt - 1)];
  __syncthreads();

  const int lane = tid & 63;
  const int wid  = tid >> 6;
  const int wm   = (wid >> 1) << 5;   // 0 / 32
  const int wn   = (wid & 1) << 5;    // 0 / 32
  const int q    = lane >> 4;         // quad 0..3
  const int r16  = lane & 15;

  // A staging: thread -> (row am, k-chunk ak)
  const int am = tid >> 2;
  const int ak = (tid & 3) << 3;
  const u16* arow = xb + (size_t)toks[am] * HD + ak;
  // B staging: thread -> (col lane, k-chunk bkw), 8 strided coalesced loads
  const int bkw = wid << 3;

  f32x4 acc[2][2] = {};

  for (int k0 = 0; k0 < HD; k0 += 32) {
    { // stage A (bf16 gather, 16B per thread)
      const uint4 av = *(const uint4*)(arow + k0);
      *(uint4*)(&As[am * LDA + ak]) = av;
    }
    { // stage B transposed: Bs[n][k], convert fp32->bf16
      const float* src = w1 + (size_t)(e * HD + k0 + bkw) * FF + n0 + lane;
      u16 tmp[8];
#pragma unroll
      for (int j = 0; j < 8; ++j) tmp[j] = f2bf(src[(size_t)j * FF]);
      uint4 bv;
      bv.x = (u32)tmp[0] | ((u32)tmp[1] << 16);
      bv.y = (u32)tmp[2] | ((u32)tmp[3] << 16);
      bv.z = (u32)tmp[4] | ((u32)tmp[5] << 16);
      bv.w = (u32)tmp[6] | ((u32)tmp[7] << 16);
      *(uint4*)(&Bs[lane * LDA + bkw]) = bv;
    }
    __syncthreads();
    bf16x8 af0 = *(const bf16x8*)(&As[(wm + r16)      * LDA + (q << 3)]);
    bf16x8 af1 = *(const bf16x8*)(&As[(wm + 16 + r16) * LDA + (q << 3)]);
    bf16x8 bf0 = *(const bf16x8*)(&Bs[(wn + r16)      * LDA + (q << 3)]);
    bf16x8 bf1 = *(const bf16x8*)(&Bs[(wn + 16 + r16) * LDA + (q << 3)]);
    acc[0][0] = __builtin_amdgcn_mfma_f32_16x16x32_bf16(af0, bf0, acc[0][0], 0, 0, 0);
    acc[0][1] = __builtin_amdgcn_mfma_f32_16x16x32_bf16(af0, bf1, acc[0][1], 0, 0, 0);
    acc[1][0] = __builtin_amdgcn_mfma_f32_16x16x32_bf16(af1, bf0, acc[1][0], 0, 0, 0);
    acc[1][1] = __builtin_amdgcn_mfma_f32_16x16x32_bf16(af1, bf1, acc[1][1], 0, 0, 0);
    __syncthreads();
  }

  // epilogue: exact gelu, store bf16. C/D: col=lane&15, row=quad*4+reg.
#pragma unroll
  for (int r = 0; r < 2; ++r) {
#pragma unroll
    for (int i = 0; i < 4; ++i) {
      const int mloc = wm + r * 16 + q * 4 + i;
      if (m0 + mloc < cnt) {
        u16* drow = hbuf + (size_t)(start + m0 + mloc) * FF + n0;
#pragma unroll
        for (int c = 0; c < 2; ++c) {
          float v = acc[r][c][i];
          v = 0.5f * v * (1.0f + erff(v * 0.70710678118f));
          drow[wn + c * 16 + r16] = f2bf(v);
        }
      }
    }
  }
}

// ---------------------------------------------------------------------------
// FFN2: out[token] += gate * ( h[slot] @ w2[e] ), K=3072, atomic accumulate.
// ---------------------------------------------------------------------------
__global__ __launch_bounds__(256) void ffn2_kernel(
    const u16* __restrict__ hbuf, const float* __restrict__ w2,
    const int* __restrict__ tos, const float* __restrict__ gos,
    const int* __restrict__ seg, float* __restrict__ out)
{
  const int e   = blockIdx.z;
  const int cnt = seg[NE + e];
  const int m0  = blockIdx.y * 64;
  if (m0 >= cnt) return;
  const int start = seg[e];
  const int n0    = blockIdx.x * 64;   // over HD=768 -> 12 tiles

  __shared__ __align__(16) u16 As[64 * LDA];
  __shared__ __align__(16) u16 Bs[64 * LDA];
  __shared__ int   toks[64];
  __shared__ float gates[64];

  const int tid = threadIdx.x;
  if (tid < 64) {
    const int idx = start + min(m0 + tid, cnt - 1);
    toks[tid]  = tos[idx];
    gates[tid] = gos[idx];
  }

  const int lane = tid & 63;
  const int wid  = tid >> 6;
  const int wm   = (wid >> 1) << 5;
  const int wn   = (wid & 1) << 5;
  const int q    = lane >> 4;
  const int r16  = lane & 15;

  const int am = tid >> 2;
  const int ak = (tid & 3) << 3;
  const u16* arow = hbuf + (size_t)(start + min(m0 + am, cnt - 1)) * FF + ak;
  const int bkw = wid << 3;

  f32x4 acc[2][2] = {};

  for (int k0 = 0; k0 < FF; k0 += 32) {
    {
      const uint4 av = *(const uint4*)(arow + k0);
      *(uint4*)(&As[am * LDA + ak]) = av;
    }
    {
      const float* src = w2 + (size_t)(e * FF + k0 + bkw) * HD + n0 + lane;
      u16 tmp[8];
#pragma unroll
      for (int j = 0; j < 8; ++j) tmp[j] = f2bf(src[(size_t)j * HD]);
      uint4 bv;
      bv.x = (u32)tmp[0] | ((u32)tmp[1] << 16);
      bv.y = (u32)tmp[2] | ((u32)tmp[3] << 16);
      bv.z = (u32)tmp[4] | ((u32)tmp[5] << 16);
      bv.w = (u32)tmp[6] | ((u32)tmp[7] << 16);
      *(uint4*)(&Bs[lane * LDA + bkw]) = bv;
    }
    __syncthreads();
    bf16x8 af0 = *(const bf16x8*)(&As[(wm + r16)      * LDA + (q << 3)]);
    bf16x8 af1 = *(const bf16x8*)(&As[(wm + 16 + r16) * LDA + (q << 3)]);
    bf16x8 bf0 = *(const bf16x8*)(&Bs[(wn + r16)      * LDA + (q << 3)]);
    bf16x8 bf1 = *(const bf16x8*)(&Bs[(wn + 16 + r16) * LDA + (q << 3)]);
    acc[0][0] = __builtin_amdgcn_mfma_f32_16x16x32_bf16(af0, bf0, acc[0][0], 0, 0, 0);
    acc[0][1] = __builtin_amdgcn_mfma_f32_16x16x32_bf16(af0, bf1, acc[0][1], 0, 0, 0);
    acc[1][0] = __builtin_amdgcn_mfma_f32_16x16x32_bf16(af1, bf0, acc[1][0], 0, 0, 0);
    acc[1][1] = __builtin_amdgcn_mfma_f32_16x16x32_bf16(af1, bf1, acc[1][1], 0, 0, 0);
    __syncthreads();
  }

#pragma unroll
  for (int r = 0; r < 2; ++r) {
#pragma unroll
    for (int i = 0; i < 4; ++i) {
      const int mloc = wm + r * 16 + q * 4 + i;
      if (m0 + mloc < cnt) {
        const int tok  = toks[mloc];
        const float g  = gates[mloc];
        float* drow = out + (size_t)tok * HD + n0;
#pragma unroll
        for (int c = 0; c < 2; ++c) {
          atomicAdd(drow + wn + c * 16 + r16, g * acc[r][c][i]);
        }
      }
    }
  }
}

// ---------------------------------------------------------------------------
extern "C" void kernel_launch(void* const* d_in, const int* in_sizes, int n_in,
                              void* d_out, int out_size, void* d_ws, size_t ws_size,
                              hipStream_t stream) {
  const float* x  = (const float*)d_in[0];
  const float* rw = (const float*)d_in[1];
  const float* w1 = (const float*)d_in[2];
  const float* w2 = (const float*)d_in[3];
  float* out = (float*)d_out;

  char* ws = (char*)d_ws;
  const size_t o_xb   = 0;                               // 1024*768*2  = 1.5 MB
  const size_t o_hbuf = o_xb + (size_t)NTOK * HD * 2;    // 2048*3072*2 = 12.6 MB
  const size_t o_tos  = o_hbuf + (size_t)NSLOT * FF * 2;
  const size_t o_gos  = o_tos + (size_t)NSLOT * 4;
  const size_t o_seg  = o_gos + (size_t)NSLOT * 4;
  u16*   xb   = (u16*)(ws + o_xb);
  u16*   hbuf = (u16*)(ws + o_hbuf);
  int*   tos  = (int*)(ws + o_tos);
  float* gos  = (float*)(ws + o_gos);
  int*   seg  = (int*)(ws + o_seg);

  hipMemsetAsync(d_out, 0, (size_t)NTOK * HD * sizeof(float), stream);
  hipLaunchKernelGGL(router_kernel, dim3(1), dim3(1024), 0, stream,
                     x, rw, xb, tos, gos, seg);
  hipLaunchKernelGGL(ffn1_kernel, dim3(FF / 64, NTOK / 64, NE), dim3(256), 0, stream,
                     xb, w1, tos, seg, hbuf);
  hipLaunchKernelGGL(ffn2_kernel, dim3(HD / 64, NTOK / 64, NE), dim3(256), 0, stream,
                     hbuf, w2, tos, gos, seg, out);
}

// Round 2
// 318.605 us; speedup vs baseline: 1.9725x; 1.9725x over previous
//
#include <hip/hip_runtime.h>
#include <cmath>

#define NTOK 1024
#define HD   768
#define FF   3072
#define NE   8
#define NSLOT (NTOK * 2)

typedef unsigned short u16;
typedef unsigned int   u32;
typedef __bf16 bf16x8 __attribute__((ext_vector_type(8)));
typedef float  f32x4  __attribute__((ext_vector_type(4)));

__device__ __forceinline__ u16 f2bf(float f) {
  union { float f; u32 u; } v; v.f = f;
  u32 r = v.u + 0x7FFFu + ((v.u >> 16) & 1u);
  return (u16)(r >> 16);
}

// ---------------------------------------------------------------------------
// Router stage A: one wave per token. Coalesced x read + bf16 convert,
// logits vs LDS-transposed router weights, wave-reduce, top-2, gates,
// per-expert position via global atomics.
// ---------------------------------------------------------------------------
__global__ __launch_bounds__(256) void router_logits(
    const float* __restrict__ x, const float* __restrict__ rw,
    u16* __restrict__ xb, int* __restrict__ counts,
    int* __restrict__ ti, int* __restrict__ tpos, float* __restrict__ tg)
{
  __shared__ float rwt[NE * HD];   // 24 KB, [e][h]
  const int tid = threadIdx.x;
  for (int i = tid; i < NE * HD; i += 256) {
    const int h = i >> 3, e = i & 7;
    rwt[e * HD + h] = rw[i];
  }
  __syncthreads();

  const int wid  = tid >> 6;
  const int lane = tid & 63;
  const int t    = blockIdx.x * 4 + wid;
  const float* xrow = x + (size_t)t * HD;
  u16* xbrow = xb + (size_t)t * HD;

  float acc[NE] = {};
#pragma unroll
  for (int j = 0; j < 12; ++j) {
    const int h = lane + j * 64;
    const float xv = xrow[h];
    xbrow[h] = f2bf(xv);
#pragma unroll
    for (int e = 0; e < NE; ++e) acc[e] += xv * rwt[e * HD + h];
  }
#pragma unroll
  for (int e = 0; e < NE; ++e) {
    float v = acc[e];
#pragma unroll
    for (int off = 32; off; off >>= 1) v += __shfl_down(v, off, 64);
    acc[e] = v;   // valid on lane 0
  }

  if (lane == 0) {
    float v0 = -1e30f, v1 = -1e30f; int i0 = 0, i1 = 0;
#pragma unroll
    for (int e = 0; e < NE; ++e) {
      const float p = acc[e];
      if (p > v0) { v1 = v0; i1 = i0; v0 = p; i0 = e; }
      else if (p > v1) { v1 = p; i1 = e; }
    }
    const float e1 = expf(v1 - v0);
    const float g0 = 1.0f / (1.0f + e1);
    const float g1 = e1 / (1.0f + e1);
    const int p0 = atomicAdd(&counts[i0], 1);
    const int p1 = atomicAdd(&counts[i1], 1);
    ti[2 * t] = i0;  ti[2 * t + 1] = i1;
    tpos[2 * t] = p0; tpos[2 * t + 1] = p1;
    tg[2 * t] = g0;  tg[2 * t + 1] = g1;
  }
}

// ---------------------------------------------------------------------------
// Router stage B: prefix-sum counts -> seg, scatter slots. 1 block, 1024 thr.
// ---------------------------------------------------------------------------
__global__ __launch_bounds__(1024) void router_scatter(
    const int* __restrict__ counts, const int* __restrict__ ti,
    const int* __restrict__ tpos, const float* __restrict__ tg,
    int* __restrict__ tos, float* __restrict__ gos, int* __restrict__ seg)
{
  __shared__ int offs[NE];
  const int t = threadIdx.x;
  if (t == 0) {
    int o = 0;
    for (int e = 0; e < NE; ++e) {
      offs[e] = o; seg[e] = o; seg[NE + e] = counts[e]; o += counts[e];
    }
  }
  __syncthreads();
  const int i0 = ti[2 * t], i1 = ti[2 * t + 1];
  const int s0 = offs[i0] + tpos[2 * t];
  const int s1 = offs[i1] + tpos[2 * t + 1];
  tos[s0] = t; gos[s0] = tg[2 * t];
  tos[s1] = t; gos[s1] = tg[2 * t + 1];
}

// ---------------------------------------------------------------------------
// FFN1: h[slot][f] = gelu( x[token[slot]] @ w1[e] ), bf16 MFMA 16x16x32.
// 64x64 tile per block, BK=32, 4 waves in 2x2 arrangement (32x32 each).
// ---------------------------------------------------------------------------
#define LDA 40

__global__ __launch_bounds__(256) void ffn1_kernel(
    const u16* __restrict__ xb, const float* __restrict__ w1,
    const int* __restrict__ tos, const int* __restrict__ seg,
    u16* __restrict__ hbuf)
{
  const int e   = blockIdx.z;
  const int cnt = seg[NE + e];
  const int m0  = blockIdx.y * 64;
  if (m0 >= cnt) return;
  const int start = seg[e];
  const int n0    = blockIdx.x * 64;

  __shared__ __align__(16) u16 As[64 * LDA];
  __shared__ __align__(16) u16 Bs[64 * LDA];
  __shared__ int toks[64];

  const int tid = threadIdx.x;
  if (tid < 64) toks[tid] = tos[start + min(m0 + tid, cnt - 1)];
  __syncthreads();

  const int lane = tid & 63;
  const int wid  = tid >> 6;
  const int wm   = (wid >> 1) << 5;
  const int wn   = (wid & 1) << 5;
  const int q    = lane >> 4;
  const int r16  = lane & 15;

  const int am = tid >> 2;
  const int ak = (tid & 3) << 3;
  const u16* arow = xb + (size_t)toks[am] * HD + ak;
  const int bkw = wid << 3;

  f32x4 acc[2][2] = {};

  for (int k0 = 0; k0 < HD; k0 += 32) {
    {
      const uint4 av = *(const uint4*)(arow + k0);
      *(uint4*)(&As[am * LDA + ak]) = av;
    }
    {
      const float* src = w1 + (size_t)(e * HD + k0 + bkw) * FF + n0 + lane;
      u16 tmp[8];
#pragma unroll
      for (int j = 0; j < 8; ++j) tmp[j] = f2bf(src[(size_t)j * FF]);
      uint4 bv;
      bv.x = (u32)tmp[0] | ((u32)tmp[1] << 16);
      bv.y = (u32)tmp[2] | ((u32)tmp[3] << 16);
      bv.z = (u32)tmp[4] | ((u32)tmp[5] << 16);
      bv.w = (u32)tmp[6] | ((u32)tmp[7] << 16);
      *(uint4*)(&Bs[lane * LDA + bkw]) = bv;
    }
    __syncthreads();
    bf16x8 af0 = *(const bf16x8*)(&As[(wm + r16)      * LDA + (q << 3)]);
    bf16x8 af1 = *(const bf16x8*)(&As[(wm + 16 + r16) * LDA + (q << 3)]);
    bf16x8 bf0 = *(const bf16x8*)(&Bs[(wn + r16)      * LDA + (q << 3)]);
    bf16x8 bf1 = *(const bf16x8*)(&Bs[(wn + 16 + r16) * LDA + (q << 3)]);
    acc[0][0] = __builtin_amdgcn_mfma_f32_16x16x32_bf16(af0, bf0, acc[0][0], 0, 0, 0);
    acc[0][1] = __builtin_amdgcn_mfma_f32_16x16x32_bf16(af0, bf1, acc[0][1], 0, 0, 0);
    acc[1][0] = __builtin_amdgcn_mfma_f32_16x16x32_bf16(af1, bf0, acc[1][0], 0, 0, 0);
    acc[1][1] = __builtin_amdgcn_mfma_f32_16x16x32_bf16(af1, bf1, acc[1][1], 0, 0, 0);
    __syncthreads();
  }

#pragma unroll
  for (int r = 0; r < 2; ++r) {
#pragma unroll
    for (int i = 0; i < 4; ++i) {
      const int mloc = wm + r * 16 + q * 4 + i;
      if (m0 + mloc < cnt) {
        u16* drow = hbuf + (size_t)(start + m0 + mloc) * FF + n0;
#pragma unroll
        for (int c = 0; c < 2; ++c) {
          float v = acc[r][c][i];
          v = 0.5f * v * (1.0f + erff(v * 0.70710678118f));
          drow[wn + c * 16 + r16] = f2bf(v);
        }
      }
    }
  }
}

// ---------------------------------------------------------------------------
// FFN2: out[token] += gate * ( h[slot] @ w2[e] ), K=3072, atomic accumulate.
// ---------------------------------------------------------------------------
__global__ __launch_bounds__(256) void ffn2_kernel(
    const u16* __restrict__ hbuf, const float* __restrict__ w2,
    const int* __restrict__ tos, const float* __restrict__ gos,
    const int* __restrict__ seg, float* __restrict__ out)
{
  const int e   = blockIdx.z;
  const int cnt = seg[NE + e];
  const int m0  = blockIdx.y * 64;
  if (m0 >= cnt) return;
  const int start = seg[e];
  const int n0    = blockIdx.x * 64;

  __shared__ __align__(16) u16 As[64 * LDA];
  __shared__ __align__(16) u16 Bs[64 * LDA];
  __shared__ int   toks[64];
  __shared__ float gates[64];

  const int tid = threadIdx.x;
  if (tid < 64) {
    const int idx = start + min(m0 + tid, cnt - 1);
    toks[tid]  = tos[idx];
    gates[tid] = gos[idx];
  }

  const int lane = tid & 63;
  const int wid  = tid >> 6;
  const int wm   = (wid >> 1) << 5;
  const int wn   = (wid & 1) << 5;
  const int q    = lane >> 4;
  const int r16  = lane & 15;

  const int am = tid >> 2;
  const int ak = (tid & 3) << 3;
  const u16* arow = hbuf + (size_t)(start + min(m0 + am, cnt - 1)) * FF + ak;
  const int bkw = wid << 3;

  f32x4 acc[2][2] = {};

  for (int k0 = 0; k0 < FF; k0 += 32) {
    {
      const uint4 av = *(const uint4*)(arow + k0);
      *(uint4*)(&As[am * LDA + ak]) = av;
    }
    {
      const float* src = w2 + (size_t)(e * FF + k0 + bkw) * HD + n0 + lane;
      u16 tmp[8];
#pragma unroll
      for (int j = 0; j < 8; ++j) tmp[j] = f2bf(src[(size_t)j * HD]);
      uint4 bv;
      bv.x = (u32)tmp[0] | ((u32)tmp[1] << 16);
      bv.y = (u32)tmp[2] | ((u32)tmp[3] << 16);
      bv.z = (u32)tmp[4] | ((u32)tmp[5] << 16);
      bv.w = (u32)tmp[6] | ((u32)tmp[7] << 16);
      *(uint4*)(&Bs[lane * LDA + bkw]) = bv;
    }
    __syncthreads();
    bf16x8 af0 = *(const bf16x8*)(&As[(wm + r16)      * LDA + (q << 3)]);
    bf16x8 af1 = *(const bf16x8*)(&As[(wm + 16 + r16) * LDA + (q << 3)]);
    bf16x8 bf0 = *(const bf16x8*)(&Bs[(wn + r16)      * LDA + (q << 3)]);
    bf16x8 bf1 = *(const bf16x8*)(&Bs[(wn + 16 + r16) * LDA + (q << 3)]);
    acc[0][0] = __builtin_amdgcn_mfma_f32_16x16x32_bf16(af0, bf0, acc[0][0], 0, 0, 0);
    acc[0][1] = __builtin_amdgcn_mfma_f32_16x16x32_bf16(af0, bf1, acc[0][1], 0, 0, 0);
    acc[1][0] = __builtin_amdgcn_mfma_f32_16x16x32_bf16(af1, bf0, acc[1][0], 0, 0, 0);
    acc[1][1] = __builtin_amdgcn_mfma_f32_16x16x32_bf16(af1, bf1, acc[1][1], 0, 0, 0);
    __syncthreads();
  }

#pragma unroll
  for (int r = 0; r < 2; ++r) {
#pragma unroll
    for (int i = 0; i < 4; ++i) {
      const int mloc = wm + r * 16 + q * 4 + i;
      if (m0 + mloc < cnt) {
        const int tok  = toks[mloc];
        const float g  = gates[mloc];
        float* drow = out + (size_t)tok * HD + n0;
#pragma unroll
        for (int c = 0; c < 2; ++c) {
          atomicAdd(drow + wn + c * 16 + r16, g * acc[r][c][i]);
        }
      }
    }
  }
}

// ---------------------------------------------------------------------------
extern "C" void kernel_launch(void* const* d_in, const int* in_sizes, int n_in,
                              void* d_out, int out_size, void* d_ws, size_t ws_size,
                              hipStream_t stream) {
  const float* x  = (const float*)d_in[0];
  const float* rw = (const float*)d_in[1];
  const float* w1 = (const float*)d_in[2];
  const float* w2 = (const float*)d_in[3];
  float* out = (float*)d_out;

  char* ws = (char*)d_ws;
  const size_t o_xb    = 0;                               // 1024*768*2  = 1.5 MB
  const size_t o_hbuf  = o_xb + (size_t)NTOK * HD * 2;    // 2048*3072*2 = 12.6 MB
  const size_t o_tos   = o_hbuf + (size_t)NSLOT * FF * 2;
  const size_t o_gos   = o_tos + (size_t)NSLOT * 4;
  const size_t o_seg   = o_gos + (size_t)NSLOT * 4;
  const size_t o_cnt   = o_seg + 64 * 4;
  const size_t o_ti    = o_cnt + NE * 4;
  const size_t o_tpos  = o_ti + (size_t)NSLOT * 4;
  const size_t o_tg    = o_tpos + (size_t)NSLOT * 4;
  u16*   xb    = (u16*)(ws + o_xb);
  u16*   hbuf  = (u16*)(ws + o_hbuf);
  int*   tos   = (int*)(ws + o_tos);
  float* gos   = (float*)(ws + o_gos);
  int*   seg   = (int*)(ws + o_seg);
  int*   cnts  = (int*)(ws + o_cnt);
  int*   ti    = (int*)(ws + o_ti);
  int*   tpos  = (int*)(ws + o_tpos);
  float* tg    = (float*)(ws + o_tg);

  hipMemsetAsync(d_out, 0, (size_t)NTOK * HD * sizeof(float), stream);
  hipMemsetAsync(cnts, 0, NE * sizeof(int), stream);
  hipLaunchKernelGGL(router_logits, dim3(NTOK / 4), dim3(256), 0, stream,
                     x, rw, xb, cnts, ti, tpos, tg);
  hipLaunchKernelGGL(router_scatter, dim3(1), dim3(1024), 0, stream,
                     cnts, ti, tpos, tg, tos, gos, seg);
  hipLaunchKernelGGL(ffn1_kernel, dim3(FF / 64, NTOK / 64, NE), dim3(256), 0, stream,
                     xb, w1, tos, seg, hbuf);
  hipLaunchKernelGGL(ffn2_kernel, dim3(HD / 64, NTOK / 64, NE), dim3(256), 0, stream,
                     hbuf, w2, tos, gos, seg, out);
}

// Round 3
// 270.684 us; speedup vs baseline: 2.3217x; 1.1770x over previous
//
#include <hip/hip_runtime.h>
#include <cmath>

#define NTOK 1024
#define HD   768
#define FF   3072
#define NE   8
#define NSLOT (NTOK * 2)
#define BK   64
#define LDK  72   // padded LDS k-stride (elems): row bank-group = row*4%32 -> 2-way on frag reads

typedef unsigned short u16;
typedef unsigned int   u32;
typedef __bf16 bf16x8 __attribute__((ext_vector_type(8)));
typedef float  f32x4  __attribute__((ext_vector_type(4)));

__device__ __forceinline__ u16 f2bf(float f) {
  union { float f; u32 u; } v; v.f = f;
  u32 r = v.u + 0x7FFFu + ((v.u >> 16) & 1u);
  return (u16)(r >> 16);
}

__device__ __forceinline__ uint4 pack8(const float* b) {
  uint4 r;
  r.x = (u32)f2bf(b[0]) | ((u32)f2bf(b[1]) << 16);
  r.y = (u32)f2bf(b[2]) | ((u32)f2bf(b[3]) << 16);
  r.z = (u32)f2bf(b[4]) | ((u32)f2bf(b[5]) << 16);
  r.w = (u32)f2bf(b[6]) | ((u32)f2bf(b[7]) << 16);
  return r;
}

// ---------------------------------------------------------------------------
// Router stage A: one wave per token.
// ---------------------------------------------------------------------------
__global__ __launch_bounds__(256) void router_logits(
    const float* __restrict__ x, const float* __restrict__ rw,
    u16* __restrict__ xb, int* __restrict__ counts,
    int* __restrict__ ti, int* __restrict__ tpos, float* __restrict__ tg)
{
  __shared__ float rwt[NE * HD];
  const int tid = threadIdx.x;
  for (int i = tid; i < NE * HD; i += 256) {
    const int h = i >> 3, e = i & 7;
    rwt[e * HD + h] = rw[i];
  }
  __syncthreads();

  const int wid  = tid >> 6;
  const int lane = tid & 63;
  const int t    = blockIdx.x * 4 + wid;
  const float* xrow = x + (size_t)t * HD;
  u16* xbrow = xb + (size_t)t * HD;

  float acc[NE] = {};
#pragma unroll
  for (int j = 0; j < 12; ++j) {
    const int h = lane + j * 64;
    const float xv = xrow[h];
    xbrow[h] = f2bf(xv);
#pragma unroll
    for (int e = 0; e < NE; ++e) acc[e] += xv * rwt[e * HD + h];
  }
#pragma unroll
  for (int e = 0; e < NE; ++e) {
    float v = acc[e];
#pragma unroll
    for (int off = 32; off; off >>= 1) v += __shfl_down(v, off, 64);
    acc[e] = v;
  }

  if (lane == 0) {
    float v0 = -1e30f, v1 = -1e30f; int i0 = 0, i1 = 0;
#pragma unroll
    for (int e = 0; e < NE; ++e) {
      const float p = acc[e];
      if (p > v0) { v1 = v0; i1 = i0; v0 = p; i0 = e; }
      else if (p > v1) { v1 = p; i1 = e; }
    }
    const float e1 = expf(v1 - v0);
    const float g0 = 1.0f / (1.0f + e1);
    const float g1 = e1 / (1.0f + e1);
    const int p0 = atomicAdd(&counts[i0], 1);
    const int p1 = atomicAdd(&counts[i1], 1);
    ti[2 * t] = i0;  ti[2 * t + 1] = i1;
    tpos[2 * t] = p0; tpos[2 * t + 1] = p1;
    tg[2 * t] = g0;  tg[2 * t + 1] = g1;
  }
}

// ---------------------------------------------------------------------------
// Router stage B: prefix-sum counts -> seg, scatter slots.
// ---------------------------------------------------------------------------
__global__ __launch_bounds__(1024) void router_scatter(
    const int* __restrict__ counts, const int* __restrict__ ti,
    const int* __restrict__ tpos, const float* __restrict__ tg,
    int* __restrict__ tos, float* __restrict__ gos, int* __restrict__ seg)
{
  __shared__ int offs[NE];
  const int t = threadIdx.x;
  if (t == 0) {
    int o = 0;
    for (int e = 0; e < NE; ++e) {
      offs[e] = o; seg[e] = o; seg[NE + e] = counts[e]; o += counts[e];
    }
  }
  __syncthreads();
  const int i0 = ti[2 * t], i1 = ti[2 * t + 1];
  const int s0 = offs[i0] + tpos[2 * t];
  const int s1 = offs[i1] + tpos[2 * t + 1];
  tos[s0] = t; gos[s0] = tg[2 * t];
  tos[s1] = t; gos[s1] = tg[2 * t + 1];
}

// ---------------------------------------------------------------------------
// FFN1: h = gelu(x_gather @ w1[e]). 64x64 tile, BK=64, register prefetch.
// ---------------------------------------------------------------------------
__global__ __launch_bounds__(256) void ffn1_kernel(
    const u16* __restrict__ xb, const float* __restrict__ w1,
    const int* __restrict__ tos, const int* __restrict__ seg,
    u16* __restrict__ hbuf)
{
  const int e   = blockIdx.z;
  const int cnt = seg[NE + e];
  const int m0  = blockIdx.y * 64;
  if (m0 >= cnt) return;
  const int start = seg[e];
  const int n0    = blockIdx.x * 64;

  __shared__ __align__(16) u16 As[64 * LDK];
  __shared__ __align__(16) u16 Bs[64 * LDK];
  __shared__ int toks[64];

  const int tid = threadIdx.x;
  if (tid < 64) toks[tid] = tos[start + min(m0 + tid, cnt - 1)];
  __syncthreads();

  // A staging: thread -> 2 chunks (rows r, r+32), 8 k-elems each
  const int ar  = tid >> 3;            // 0..31
  const int akc = (tid & 7) << 3;      // 0..56
  const u16* asrc0 = xb + (size_t)toks[ar]      * HD + akc;
  const u16* asrc1 = xb + (size_t)toks[ar + 32] * HD + akc;
  const int adst0 = ar * LDK + akc;
  const int adst1 = (ar + 32) * LDK + akc;
  // B staging: thread -> n=tid&63, k-chunks bkc and bkc+32 (8 strided dwords each)
  const int bn  = tid & 63;
  const int bkc = (tid >> 6) << 3;     // 0,8,16,24
  const float* bsrc0 = w1 + ((size_t)e * HD + bkc) * FF + n0 + bn;
  const float* bsrc1 = bsrc0 + (size_t)32 * FF;
  const int bdst0 = bn * LDK + bkc;
  const int bdst1 = bn * LDK + bkc + 32;

  const int lane = tid & 63;
  const int wid  = tid >> 6;
  const int wm   = (wid >> 1) << 5;
  const int wn   = (wid & 1) << 5;
  const int q    = lane >> 4;
  const int r16  = lane & 15;

  uint4 areg0, areg1;
  float breg0[8], breg1[8];

#define FFN_LOAD(K0)                                                        \
  do {                                                                      \
    areg0 = *(const uint4*)(asrc0 + (K0));                                  \
    areg1 = *(const uint4*)(asrc1 + (K0));                                  \
    _Pragma("unroll")                                                       \
    for (int j = 0; j < 8; ++j) breg0[j] = bsrc0[(size_t)((K0) + j) * FF];  \
    _Pragma("unroll")                                                       \
    for (int j = 0; j < 8; ++j) breg1[j] = bsrc1[(size_t)((K0) + j) * FF];  \
  } while (0)

  FFN_LOAD(0);
  f32x4 acc[2][2] = {};

  for (int k0 = 0;;) {
    const uint4 bw0 = pack8(breg0);
    const uint4 bw1 = pack8(breg1);
    __syncthreads();
    *(uint4*)(&As[adst0]) = areg0;
    *(uint4*)(&As[adst1]) = areg1;
    *(uint4*)(&Bs[bdst0]) = bw0;
    *(uint4*)(&Bs[bdst1]) = bw1;
    __syncthreads();
    k0 += BK;
    if (k0 < HD) { FFN_LOAD(k0); }
#pragma unroll
    for (int s = 0; s < 2; ++s) {
      const int ko = s * 32 + (q << 3);
      bf16x8 a0 = *(const bf16x8*)(&As[(wm + r16)      * LDK + ko]);
      bf16x8 a1 = *(const bf16x8*)(&As[(wm + 16 + r16) * LDK + ko]);
      bf16x8 b0 = *(const bf16x8*)(&Bs[(wn + r16)      * LDK + ko]);
      bf16x8 b1 = *(const bf16x8*)(&Bs[(wn + 16 + r16) * LDK + ko]);
      acc[0][0] = __builtin_amdgcn_mfma_f32_16x16x32_bf16(a0, b0, acc[0][0], 0, 0, 0);
      acc[0][1] = __builtin_amdgcn_mfma_f32_16x16x32_bf16(a0, b1, acc[0][1], 0, 0, 0);
      acc[1][0] = __builtin_amdgcn_mfma_f32_16x16x32_bf16(a1, b0, acc[1][0], 0, 0, 0);
      acc[1][1] = __builtin_amdgcn_mfma_f32_16x16x32_bf16(a1, b1, acc[1][1], 0, 0, 0);
    }
    if (k0 >= HD) break;
  }

#pragma unroll
  for (int r = 0; r < 2; ++r) {
#pragma unroll
    for (int i = 0; i < 4; ++i) {
      const int mloc = wm + r * 16 + q * 4 + i;
      if (m0 + mloc < cnt) {
        u16* drow = hbuf + (size_t)(start + m0 + mloc) * FF + n0;
#pragma unroll
        for (int c = 0; c < 2; ++c) {
          float v = acc[r][c][i];
          v = 0.5f * v * (1.0f + erff(v * 0.70710678118f));
          drow[wn + c * 16 + r16] = f2bf(v);
        }
      }
    }
  }
}

// ---------------------------------------------------------------------------
// FFN2: out += gate * (h @ w2[e]). 64x64 tile, BK=64, K-split x2, prefetch.
// ---------------------------------------------------------------------------
#define KSPLIT 2
#define KSEG   (FF / KSPLIT)   // 1536

__global__ __launch_bounds__(256) void ffn2_kernel(
    const u16* __restrict__ hbuf, const float* __restrict__ w2,
    const int* __restrict__ tos, const float* __restrict__ gos,
    const int* __restrict__ seg, float* __restrict__ out)
{
  const int ez  = blockIdx.z;
  const int e   = ez >> 1;
  const int ks  = ez & 1;
  const int cnt = seg[NE + e];
  const int m0  = blockIdx.y * 64;
  if (m0 >= cnt) return;
  const int start = seg[e];
  const int n0    = blockIdx.x * 64;
  const int kbase = ks * KSEG;

  __shared__ __align__(16) u16 As[64 * LDK];
  __shared__ __align__(16) u16 Bs[64 * LDK];
  __shared__ int   toks[64];
  __shared__ float gates[64];

  const int tid = threadIdx.x;
  if (tid < 64) {
    const int idx = start + min(m0 + tid, cnt - 1);
    toks[tid]  = tos[idx];
    gates[tid] = gos[idx];
  }
  __syncthreads();

  const int ar  = tid >> 3;
  const int akc = (tid & 7) << 3;
  const u16* asrc0 = hbuf + (size_t)(start + min(m0 + ar,      cnt - 1)) * FF + kbase + akc;
  const u16* asrc1 = hbuf + (size_t)(start + min(m0 + ar + 32, cnt - 1)) * FF + kbase + akc;
  const int adst0 = ar * LDK + akc;
  const int adst1 = (ar + 32) * LDK + akc;
  const int bn  = tid & 63;
  const int bkc = (tid >> 6) << 3;
  const float* bsrc0 = w2 + ((size_t)e * FF + kbase + bkc) * HD + n0 + bn;
  const float* bsrc1 = bsrc0 + (size_t)32 * HD;
  const int bdst0 = bn * LDK + bkc;
  const int bdst1 = bn * LDK + bkc + 32;

  const int lane = tid & 63;
  const int wid  = tid >> 6;
  const int wm   = (wid >> 1) << 5;
  const int wn   = (wid & 1) << 5;
  const int q    = lane >> 4;
  const int r16  = lane & 15;

  uint4 areg0, areg1;
  float breg0[8], breg1[8];

#define FFN2_LOAD(K0)                                                       \
  do {                                                                      \
    areg0 = *(const uint4*)(asrc0 + (K0));                                  \
    areg1 = *(const uint4*)(asrc1 + (K0));                                  \
    _Pragma("unroll")                                                       \
    for (int j = 0; j < 8; ++j) breg0[j] = bsrc0[(size_t)((K0) + j) * HD];  \
    _Pragma("unroll")                                                       \
    for (int j = 0; j < 8; ++j) breg1[j] = bsrc1[(size_t)((K0) + j) * HD];  \
  } while (0)

  FFN2_LOAD(0);
  f32x4 acc[2][2] = {};

  for (int k0 = 0;;) {
    const uint4 bw0 = pack8(breg0);
    const uint4 bw1 = pack8(breg1);
    __syncthreads();
    *(uint4*)(&As[adst0]) = areg0;
    *(uint4*)(&As[adst1]) = areg1;
    *(uint4*)(&Bs[bdst0]) = bw0;
    *(uint4*)(&Bs[bdst1]) = bw1;
    __syncthreads();
    k0 += BK;
    if (k0 < KSEG) { FFN2_LOAD(k0); }
#pragma unroll
    for (int s = 0; s < 2; ++s) {
      const int ko = s * 32 + (q << 3);
      bf16x8 a0 = *(const bf16x8*)(&As[(wm + r16)      * LDK + ko]);
      bf16x8 a1 = *(const bf16x8*)(&As[(wm + 16 + r16) * LDK + ko]);
      bf16x8 b0 = *(const bf16x8*)(&Bs[(wn + r16)      * LDK + ko]);
      bf16x8 b1 = *(const bf16x8*)(&Bs[(wn + 16 + r16) * LDK + ko]);
      acc[0][0] = __builtin_amdgcn_mfma_f32_16x16x32_bf16(a0, b0, acc[0][0], 0, 0, 0);
      acc[0][1] = __builtin_amdgcn_mfma_f32_16x16x32_bf16(a0, b1, acc[0][1], 0, 0, 0);
      acc[1][0] = __builtin_amdgcn_mfma_f32_16x16x32_bf16(a1, b0, acc[1][0], 0, 0, 0);
      acc[1][1] = __builtin_amdgcn_mfma_f32_16x16x32_bf16(a1, b1, acc[1][1], 0, 0, 0);
    }
    if (k0 >= KSEG) break;
  }

#pragma unroll
  for (int r = 0; r < 2; ++r) {
#pragma unroll
    for (int i = 0; i < 4; ++i) {
      const int mloc = wm + r * 16 + q * 4 + i;
      if (m0 + mloc < cnt) {
        const int tok  = toks[mloc];
        const float g  = gates[mloc];
        float* drow = out + (size_t)tok * HD + n0;
#pragma unroll
        for (int c = 0; c < 2; ++c) {
          atomicAdd(drow + wn + c * 16 + r16, g * acc[r][c][i]);
        }
      }
    }
  }
}

// ---------------------------------------------------------------------------
extern "C" void kernel_launch(void* const* d_in, const int* in_sizes, int n_in,
                              void* d_out, int out_size, void* d_ws, size_t ws_size,
                              hipStream_t stream) {
  const float* x  = (const float*)d_in[0];
  const float* rw = (const float*)d_in[1];
  const float* w1 = (const float*)d_in[2];
  const float* w2 = (const float*)d_in[3];
  float* out = (float*)d_out;

  char* ws = (char*)d_ws;
  const size_t o_xb    = 0;
  const size_t o_hbuf  = o_xb + (size_t)NTOK * HD * 2;
  const size_t o_tos   = o_hbuf + (size_t)NSLOT * FF * 2;
  const size_t o_gos   = o_tos + (size_t)NSLOT * 4;
  const size_t o_seg   = o_gos + (size_t)NSLOT * 4;
  const size_t o_cnt   = o_seg + 64 * 4;
  const size_t o_ti    = o_cnt + NE * 4;
  const size_t o_tpos  = o_ti + (size_t)NSLOT * 4;
  const size_t o_tg    = o_tpos + (size_t)NSLOT * 4;
  u16*   xb    = (u16*)(ws + o_xb);
  u16*   hbuf  = (u16*)(ws + o_hbuf);
  int*   tos   = (int*)(ws + o_tos);
  float* gos   = (float*)(ws + o_gos);
  int*   seg   = (int*)(ws + o_seg);
  int*   cnts  = (int*)(ws + o_cnt);
  int*   ti    = (int*)(ws + o_ti);
  int*   tpos  = (int*)(ws + o_tpos);
  float* tg    = (float*)(ws + o_tg);

  hipMemsetAsync(d_out, 0, (size_t)NTOK * HD * sizeof(float), stream);
  hipMemsetAsync(cnts, 0, NE * sizeof(int), stream);
  hipLaunchKernelGGL(router_logits, dim3(NTOK / 4), dim3(256), 0, stream,
                     x, rw, xb, cnts, ti, tpos, tg);
  hipLaunchKernelGGL(router_scatter, dim3(1), dim3(1024), 0, stream,
                     cnts, ti, tpos, tg, tos, gos, seg);
  hipLaunchKernelGGL(ffn1_kernel, dim3(FF / 64, NTOK / 64, NE), dim3(256), 0, stream,
                     xb, w1, tos, seg, hbuf);
  hipLaunchKernelGGL(ffn2_kernel, dim3(HD / 64, NTOK / 64, NE * KSPLIT), dim3(256), 0, stream,
                     hbuf, w2, tos, gos, seg, out);
}